// Round 2
// baseline (359.248 us; speedup 1.0000x reference)
//
#include <hip/hip_runtime.h>
#include <stdint.h>

// B=8, C=64, N=4096. Flash attention with Q=K=x^T [N,64], V=x^T W [N,64].
// Round 2: split-K (KS chunks) for occupancy + fixed per-row stabilizer
// m = ||q||^2 (no online-softmax rescaling; partials directly addable).

#define NTOK 4096
#define CCH  64

typedef float v4f __attribute__((ext_vector_type(4)));
typedef __bf16 v8bf __attribute__((ext_vector_type(8)));
typedef unsigned short v8us __attribute__((ext_vector_type(8)));

__device__ __forceinline__ unsigned short f2bf(float f) {
    union { float f; unsigned int u; } c; c.f = f;
    unsigned int r = c.u + 0x7fffu + ((c.u >> 16) & 1u);   // RNE
    return (unsigned short)(r >> 16);
}

__device__ __forceinline__ v8bf ld_bf8(const unsigned short* p) {
    union { v8us s; v8bf b; } u;
    u.s = *(const v8us*)p;
    return u.b;
}

// pack two f32 -> u32 holding (bf16(a) | bf16(b)<<16), truncation, 1 v_perm
__device__ __forceinline__ unsigned int pkbf(float a, float b) {
    union { float f; unsigned int u; } ua, ub; ua.f = a; ub.f = b;
    return __builtin_amdgcn_perm(ub.u, ua.u, 0x07060302u);
}

// ---------------------------------------------------------------------------
// Prep: xT[b][n][c] = bf16(x[b][c][n]);  sT[b][d][n] = bf16(sum_c x[b][c][n] W[c][d])
// W is wave-uniform -> scalarized s_load; accumulators live in VGPRs.
// ---------------------------------------------------------------------------
__global__ __launch_bounds__(256, 2) void prep_kernel(
    const float* __restrict__ x,        // [8][64][4096]
    const float* __restrict__ w,        // [64][64]
    unsigned short* __restrict__ xT,    // [8][4096][64] bf16
    unsigned short* __restrict__ sT)    // [8][64][4096] bf16
{
    const int tid = threadIdx.x;
    const int b = blockIdx.y;
    const int n = blockIdx.x * 256 + tid;
    const float* xb = x + (size_t)b * CCH * NTOK;
    unsigned short* xtrow = xT + ((size_t)b * NTOK + n) * CCH;

    float acc[64];
    #pragma unroll
    for (int d = 0; d < 64; ++d) acc[d] = 0.f;

    for (int c = 0; c < 64; ++c) {
        float xc = xb[(size_t)c * NTOK + n];     // coalesced
        xtrow[c] = f2bf(xc);
        #pragma unroll
        for (int d = 0; d < 64; ++d) acc[d] = fmaf(xc, w[c * 64 + d], acc[d]);
    }
    unsigned short* stb = sT + (size_t)b * CCH * NTOK + n;
    #pragma unroll
    for (int d = 0; d < 64; ++d) stb[(size_t)d * NTOK] = f2bf(acc[d]);   // coalesced
}

// ---------------------------------------------------------------------------
// Flash chunk kernel. Grid: (64 i-tiles, KS chunks, 8 batches) x 256 thr.
// Wave owns 16 Q rows; j-tile = 64 cols; fixed m = ||q||^2 per row.
// Writes unnormalized partial O (C-layout rowsxcols) + partial sum l.
// MFMA 16x16x32 bf16: A[m=l16][k=quad*8+j]  B[k=quad*8+j][n=l16]
//                     C/D[row=quad*4+r][col=l16]
// ---------------------------------------------------------------------------
__global__ __launch_bounds__(256, 6) void flash_kernel(
    const unsigned short* __restrict__ xT,   // [8][4096][64]
    const unsigned short* __restrict__ sT,   // [8][64][4096]
    float* __restrict__ part_o,              // [8][KS][4096][64]
    float* __restrict__ part_l,              // [8][KS][4096]
    int nchunk, int chunk_len)
{
    // per-wave 16x64 f32 P tile, row stride 68 (16B-aligned, 2-way banks max)
    __shared__ __align__(16) float Pl[4][16 * 68];

    const int tid  = threadIdx.x;
    const int w    = tid >> 6;
    const int lane = tid & 63;
    const int quad = lane >> 4;
    const int l16  = lane & 15;
    const int b    = blockIdx.z;
    const int chunk = blockIdx.y;
    const int i0   = blockIdx.x * 64;
    const int irow = i0 + 16 * w;
    const int jb   = chunk * chunk_len;

    const unsigned short* xTb = xT + (size_t)b * NTOK * CCH;
    const unsigned short* sTb = sT + (size_t)b * CCH * NTOK;

    const v8bf aq0 = ld_bf8(xTb + (size_t)(irow + l16) * CCH + quad * 8);
    const v8bf aq1 = ld_bf8(xTb + (size_t)(irow + l16) * CCH + 32 + quad * 8);

    // m_row = ||q_row||^2 from bf16 frags (bitwise identical across chunks)
    float msq = 0.f;
    #pragma unroll
    for (int i = 0; i < 8; ++i) {
        float e0 = (float)aq0[i], e1 = (float)aq1[i];
        msq = fmaf(e0, e0, msq);
        msq = fmaf(e1, e1, msq);
    }
    msq += __shfl_xor(msq, 16);
    msq += __shfl_xor(msq, 32);
    float negm[4];
    #pragma unroll
    for (int r = 0; r < 4; ++r) negm[r] = -__shfl(msq, quad * 4 + r);

    v4f o[4];
    #pragma unroll
    for (int ct = 0; ct < 4; ++ct) { o[ct][0]=0.f; o[ct][1]=0.f; o[ct][2]=0.f; o[ct][3]=0.f; }
    float rsum[4] = {0.f, 0.f, 0.f, 0.f};

    float* Pw = Pl[w];
    const float* Pr0 = Pw + l16 * 68 + quad * 8;

    for (int jj = 0; jj < chunk_len; jj += 64) {
        const int j0 = jb + jj;

        // ---- S = Q K^T ----
        v4f s[4];
        #pragma unroll
        for (int jt = 0; jt < 4; ++jt) {
            const unsigned short* kr = xTb + (size_t)(j0 + 16 * jt + l16) * CCH + quad * 8;
            v8bf bk0 = ld_bf8(kr);
            v8bf bk1 = ld_bf8(kr + 32);
            v4f z; z[0]=0.f; z[1]=0.f; z[2]=0.f; z[3]=0.f;
            z     = __builtin_amdgcn_mfma_f32_16x16x32_bf16(aq0, bk0, z, 0, 0, 0);
            s[jt] = __builtin_amdgcn_mfma_f32_16x16x32_bf16(aq1, bk1, z, 0, 0, 0);
        }

        // ---- p = exp(s - m), accumulate per-lane sum, stage f32 P ----
        #pragma unroll
        for (int jt = 0; jt < 4; ++jt) {
            #pragma unroll
            for (int r = 0; r < 4; ++r) {
                float p = __expf(s[jt][r] + negm[r]);
                rsum[r] += p;
                Pw[(quad * 4 + r) * 68 + 16 * jt + l16] = p;
            }
        }

        // ---- read back in A-layout (wave-local; no barrier) + pack bf16 ----
        v4f f0 = *(const v4f*)(Pr0);
        v4f f1 = *(const v4f*)(Pr0 + 4);
        v4f f2 = *(const v4f*)(Pr0 + 32);
        v4f f3 = *(const v4f*)(Pr0 + 36);
        union { unsigned int u[4]; v8bf b; } pa0, pa1;
        pa0.u[0] = pkbf(f0[0], f0[1]); pa0.u[1] = pkbf(f0[2], f0[3]);
        pa0.u[2] = pkbf(f1[0], f1[1]); pa0.u[3] = pkbf(f1[2], f1[3]);
        pa1.u[0] = pkbf(f2[0], f2[1]); pa1.u[1] = pkbf(f2[2], f2[3]);
        pa1.u[2] = pkbf(f3[0], f3[1]); pa1.u[3] = pkbf(f3[2], f3[3]);

        // ---- O += P V ----
        #pragma unroll
        for (int ct = 0; ct < 4; ++ct) {
            const unsigned short* vr = sTb + (size_t)(16 * ct + l16) * NTOK + j0 + quad * 8;
            v8bf bv0 = ld_bf8(vr);
            v8bf bv1 = ld_bf8(vr + 32);
            o[ct] = __builtin_amdgcn_mfma_f32_16x16x32_bf16(pa0.b, bv0, o[ct], 0, 0, 0);
            o[ct] = __builtin_amdgcn_mfma_f32_16x16x32_bf16(pa1.b, bv1, o[ct], 0, 0, 0);
        }
    }

    // ---- epilogue: reduce row sums once, store partials ----
    #pragma unroll
    for (int r = 0; r < 4; ++r) {
        float t = rsum[r];
        t += __shfl_xor(t, 1);
        t += __shfl_xor(t, 2);
        t += __shfl_xor(t, 4);
        t += __shfl_xor(t, 8);
        rsum[r] = t;
    }
    const size_t pbase = (size_t)(b * nchunk + chunk) * NTOK + irow;
    if (l16 == 0) {
        #pragma unroll
        for (int r = 0; r < 4; ++r) part_l[pbase + quad * 4 + r] = rsum[r];
    }
    float* po = part_o + pbase * 64;
    #pragma unroll
    for (int ct = 0; ct < 4; ++ct) {
        #pragma unroll
        for (int r = 0; r < 4; ++r)
            po[(size_t)(quad * 4 + r) * 64 + 16 * ct + l16] = o[ct][r];
    }
}

// ---------------------------------------------------------------------------
// Combine: sum chunk partials, normalize, transpose, add x, store.
// Grid: (64 i-tiles, 8 batches) x 256 threads.
// ---------------------------------------------------------------------------
__global__ __launch_bounds__(256, 2) void combine_kernel(
    const float* __restrict__ part_o,  // [8][KS][4096][64]
    const float* __restrict__ part_l,  // [8][KS][4096]
    const float* __restrict__ x,       // [8][64][4096]
    float* __restrict__ out,           // [8][64][4096]
    int nchunk)
{
    __shared__ float Of[64 * 65];
    const int tid = threadIdx.x;
    const int b = blockIdx.y;
    const int i0 = blockIdx.x * 64;
    const int row = tid >> 2;          // local n 0..63
    const int seg = tid & 3;           // 16-col segment

    float acc[16];
    #pragma unroll
    for (int k = 0; k < 16; ++k) acc[k] = 0.f;
    float lt = 0.f;

    for (int ch = 0; ch < nchunk; ++ch) {
        const size_t base = (size_t)(b * nchunk + ch) * NTOK + i0 + row;
        lt += part_l[base];
        const float* po = part_o + base * 64 + seg * 16;
        #pragma unroll
        for (int k = 0; k < 4; ++k) {
            float4 v = *(const float4*)(po + k * 4);
            acc[k*4+0] += v.x; acc[k*4+1] += v.y; acc[k*4+2] += v.z; acc[k*4+3] += v.w;
        }
    }
    const float inv = 1.f / lt;
    #pragma unroll
    for (int k = 0; k < 16; ++k) Of[row * 65 + seg * 16 + k] = acc[k] * inv;
    __syncthreads();

    const int c    = tid >> 2;
    const int part = tid & 3;
    const float* xrow = x   + ((size_t)b * CCH + c) * NTOK + i0 + part * 16;
    float*       orow = out + ((size_t)b * CCH + c) * NTOK + i0 + part * 16;
    #pragma unroll
    for (int i4 = 0; i4 < 4; ++i4) {
        float4 xv = *(const float4*)(xrow + i4 * 4);
        float4 ov;
        ov.x = Of[(part * 16 + i4 * 4 + 0) * 65 + c] + xv.x;
        ov.y = Of[(part * 16 + i4 * 4 + 1) * 65 + c] + xv.y;
        ov.z = Of[(part * 16 + i4 * 4 + 2) * 65 + c] + xv.z;
        ov.w = Of[(part * 16 + i4 * 4 + 3) * 65 + c] + xv.w;
        *(float4*)(orow + i4 * 4) = ov;
    }
}

// ---------------------------------------------------------------------------
extern "C" void kernel_launch(void* const* d_in, const int* in_sizes, int n_in,
                              void* d_out, int out_size, void* d_ws, size_t ws_size,
                              hipStream_t stream) {
    const float* x = (const float*)d_in[0];
    const float* w = (const float*)d_in[1];
    float* out = (float*)d_out;

    const size_t xT_elems = (size_t)8 * NTOK * CCH;         // 2M shorts = 4 MB
    unsigned short* xT = (unsigned short*)d_ws;
    unsigned short* sT = xT + xT_elems;
    char* rest = (char*)d_ws + 2 * xT_elems * sizeof(unsigned short);   // +8 MB

    // pick split factor that fits the workspace
    int KS = 4;
    while (KS > 1) {
        size_t need = 2 * xT_elems * sizeof(unsigned short)
                    + (size_t)KS * ((size_t)8 * NTOK * CCH * 4 + (size_t)8 * NTOK * 4);
        if (need <= ws_size) break;
        KS >>= 1;
    }
    float* part_o = (float*)rest;                                       // KS*8 MB
    float* part_l = (float*)(rest + (size_t)KS * 8 * NTOK * CCH * 4);   // KS*128 KB

    dim3 gp(16, 8);
    prep_kernel<<<gp, 256, 0, stream>>>(x, w, xT, sT);
    dim3 gf(64, KS, 8);
    flash_kernel<<<gf, 256, 0, stream>>>(xT, sT, part_o, part_l, KS, NTOK / KS);
    dim3 gc(64, 8);
    combine_kernel<<<gc, 256, 0, stream>>>(part_o, part_l, x, out, KS);
}